// Round 2
// baseline (1014.556 us; speedup 1.0000x reference)
//
#include <hip/hip_runtime.h>
#include <hip/hip_bf16.h>
#include <climits>

#define SEG_B 64
#define SEG_L 50000
#define SEG_D 32
#define TOPK  1024
#define NB1   4096      // round-1 bins (top 12 bits of ordkey)
#define CAP   8192      // per-segment candidate cap (expected ~2300)

// Map float to uint32 such that larger float -> larger key (total order, no NaN in inputs).
__device__ __forceinline__ unsigned ordkey(float f) {
    unsigned u = __float_as_uint(f);
    return (u & 0x80000000u) ? ~u : (u | 0x80000000u);
}

// Pass 1: att[p] = dot(x[p,:32], w) + bias, plus per-segment 4096-bin histogram
// of the top-12 ordkey bits. 8 lanes per point, float4 loads (1 KiB/wave/instr).
__global__ void k_att(const float* __restrict__ x, const float* __restrict__ w,
                      const float* __restrict__ bias, float* __restrict__ att,
                      unsigned* __restrict__ hist) {
    const int lane = threadIdx.x & 63;
    const int q    = lane & 7;      // which float4 of the 32-dim row
    const int sub  = lane >> 3;     // which of the 8 points this wave handles per iter
    const int waveInBlock   = threadIdx.x >> 6;
    const int wavesPerBlock = blockDim.x >> 6;
    const int waveId     = blockIdx.x * wavesPerBlock + waveInBlock;
    const int totalWaves = gridDim.x * wavesPerBlock;
    const float4 wq = ((const float4*)w)[q];
    const float bb  = bias[0];
    const float4* x4 = (const float4*)x;
    const int N = SEG_B * SEG_L;
    for (int p = waveId * 8 + sub; p < N; p += totalWaves * 8) {
        float4 v = x4[(size_t)p * 8 + q];
        float dot = v.x * wq.x + v.y * wq.y + v.z * wq.z + v.w * wq.w;
        dot += __shfl_xor(dot, 1);
        dot += __shfl_xor(dot, 2);
        dot += __shfl_xor(dot, 4);
        if (q == 0) {
            float a = dot + bb;
            att[p] = a;
            unsigned key = ordkey(a);
            int b = p / SEG_L;
            atomicAdd(&hist[b * NB1 + (key >> 20)], 1u);
        }
    }
}

// Pass 2: per-segment parallel suffix-scan of the 4096-bin histogram ->
// boundary digit b1 (smallest digit with suffix count >= TOPK) and k1 = rank within bin.
__global__ void k_bound(const unsigned* __restrict__ hist, uint2* __restrict__ bsel) {
    const int b = blockIdx.x;
    const int t = threadIdx.x;       // 1024 threads, 4 bins each
    __shared__ unsigned sscan[1024];
    const uint4* h4 = (const uint4*)(hist + b * NB1);
    uint4 c = h4[t];                 // bins 4t..4t+3
    unsigned cl[4] = {c.x, c.y, c.z, c.w};
    unsigned gs = cl[0] + cl[1] + cl[2] + cl[3];
    sscan[t] = gs;
    __syncthreads();
    for (int off = 1; off < 1024; off <<= 1) {
        unsigned v = (t + off < 1024) ? sscan[t + off] : 0u;
        __syncthreads();
        sscan[t] += v;
        __syncthreads();
    }
    unsigned above = sscan[t] - gs;  // sum over bins of groups > t
    unsigned run = above;
    #pragma unroll
    for (int j = 3; j >= 0; --j) {
        unsigned nr = run + cl[j];
        if (run < TOPK && nr >= TOPK) {
            // boundary bin: strictly-greater bins hold `run`; need TOPK-run from this bin
            bsel[b] = make_uint2((unsigned)(4 * t + j), (unsigned)(TOPK - run));
        }
        run = nr;
    }
}

// Pass 3: single warm pass over att; append (key, idx) for digit >= b1 (candidates).
__global__ void k_gather(const float* __restrict__ att, const uint2* __restrict__ bsel,
                         unsigned* __restrict__ cand_cnt, uint2* __restrict__ cand) {
    const int b = blockIdx.x;
    const unsigned b1 = bsel[b].x;
    const int per = (SEG_L + gridDim.y - 1) / gridDim.y;
    const int start = blockIdx.y * per;
    const int end = min(start + per, SEG_L);
    for (int i = start + (int)threadIdx.x; i < end; i += (int)blockDim.x) {
        unsigned key = ordkey(att[(size_t)b * SEG_L + i]);
        if ((key >> 20) >= b1) {
            unsigned pos = atomicAdd(&cand_cnt[b], 1u);
            if (pos < CAP) cand[b * CAP + pos] = make_uint2(key, (unsigned)i);
        }
    }
}

// Pass 4: per-segment: exact radix select over candidates (in LDS, parallel scans),
// gather+sum the selected rows, tie-break, mean over L, L2-normalize, write out.
__global__ void __launch_bounds__(1024)
k_phase2(const float* __restrict__ x, const uint2* __restrict__ cand,
         const unsigned* __restrict__ cand_cnt, float* __restrict__ out) {
    const int b = blockIdx.x;
    const int tid = threadIdx.x;     // 1024 threads
    __shared__ unsigned skey[CAP];
    __shared__ unsigned sidx[CAP];
    __shared__ unsigned hist[2048];
    __shared__ unsigned sscan[1024];
    __shared__ float    sred[32][33];
    __shared__ float    s_res[32];
    __shared__ int      s_eq[64];
    __shared__ int      s_eqsel[64];
    __shared__ unsigned s_prefix, s_k, s_eqn;
    __shared__ float    s_norm;

    const int cnt = min((int)cand_cnt[b], CAP);
    for (int c = tid; c < cnt; c += 1024) {
        uint2 v = cand[b * CAP + c];
        skey[c] = v.x; sidx[c] = v.y;
    }
    if (tid == 0) { s_prefix = 0u; s_k = TOPK; s_eqn = 0u; }
    __syncthreads();

    const unsigned shifts[3]   = {21u, 10u, 0u};
    const unsigned widths[3]   = {11u, 11u, 10u};
    const unsigned maskdone[3] = {0x00000000u, 0xFFE00000u, 0xFFFFFC00u};

    for (int r = 0; r < 3; ++r) {
        const unsigned shift = shifts[r];
        const int      nbins = 1 << widths[r];
        const unsigned dmask = (unsigned)nbins - 1u;
        const unsigned mdone = maskdone[r];
        const int      bpt   = nbins >> 10;             // bins per thread: 2 or 1
        for (int i = tid; i < nbins; i += 1024) hist[i] = 0u;
        __syncthreads();
        const unsigned prefix = s_prefix;
        const unsigned kneed  = s_k;
        for (int c = tid; c < cnt; c += 1024) {
            unsigned key = skey[c];
            if ((key & mdone) == prefix) atomicAdd(&hist[(key >> shift) & dmask], 1u);
        }
        __syncthreads();
        unsigned cl[2] = {0u, 0u};
        unsigned gs = 0u;
        for (int j = 0; j < bpt; ++j) { cl[j] = hist[tid * bpt + j]; gs += cl[j]; }
        sscan[tid] = gs;
        __syncthreads();
        for (int off = 1; off < 1024; off <<= 1) {
            unsigned v = (tid + off < 1024) ? sscan[tid + off] : 0u;
            __syncthreads();
            sscan[tid] += v;
            __syncthreads();
        }
        unsigned run = sscan[tid] - gs;                  // strictly above this thread's bins
        for (int j = bpt - 1; j >= 0; --j) {
            unsigned nr = run + cl[j];
            if (run < kneed && nr >= kneed) {
                s_prefix = prefix | ((unsigned)(tid * bpt + j) << shift);
                s_k = kneed - run;
            }
            run = nr;
        }
        __syncthreads();
    }

    const unsigned tk = s_prefix;                        // threshold key
    const int m = (int)s_k;                              // equals needed

    // Sum rows with key > tk: 32 row-groups x 32 dims.
    const int rg = tid >> 5, d = tid & 31;
    float part = 0.0f;
    for (int c = rg; c < cnt; c += 32) {
        if (skey[c] > tk) part += x[((size_t)b * SEG_L + sidx[c]) * SEG_D + d];
    }
    sred[rg][d] = part;
    // Collect indices equal to threshold.
    for (int c = tid; c < cnt; c += 1024) {
        if (skey[c] == tk) {
            unsigned p = atomicAdd(&s_eqn, 1u);
            if (p < 64u) s_eq[p] = (int)sidx[c];
        }
    }
    __syncthreads();
    if (tid == 0) {
        int eqn = (int)min(s_eqn, 64u);
        int mm = min(m, eqn);
        int last = -1;
        for (int j = 0; j < mm; ++j) {                   // m is ~1; tiny serial select
            int best = INT_MAX;
            for (int t2 = 0; t2 < eqn; ++t2) {
                int v = s_eq[t2];
                if (v > last && v < best) best = v;
            }
            s_eqsel[j] = best;
            last = best;
        }
    }
    __syncthreads();
    if (tid < 32) {
        float s = 0.0f;
        for (int r2 = 0; r2 < 32; ++r2) s += sred[r2][tid];
        int eqn = (int)min(s_eqn, 64u);
        int mm = min(m, eqn);
        for (int j = 0; j < mm; ++j) {
            int row = s_eqsel[j];
            if (row != INT_MAX) s += x[((size_t)b * SEG_L + row) * SEG_D + tid];
        }
        s_res[tid] = s / (float)SEG_L;
    }
    __syncthreads();
    if (tid == 0) {
        float n = 0.0f;
        for (int i = 0; i < SEG_D; ++i) n += s_res[i] * s_res[i];
        s_norm = sqrtf(n);
    }
    __syncthreads();
    if (tid < 32) out[b * SEG_D + tid] = s_res[tid] / fmaxf(s_norm, 1e-12f);
}

extern "C" void kernel_launch(void* const* d_in, const int* in_sizes, int n_in,
                              void* d_out, int out_size, void* d_ws, size_t ws_size,
                              hipStream_t stream) {
    const float* x    = (const float*)d_in[0];   // [B*L, 32] fp32
    // d_in[1] = length (int32[64]) — constant L, unused
    const float* w    = (const float*)d_in[2];   // [32]
    const float* bias = (const float*)d_in[3];   // [1]
    float* out = (float*)d_out;                  // [64, 32]

    // Workspace layout (regions 256B-aligned by construction):
    char* p = (char*)d_ws;
    float*    att      = (float*)p;    p += (size_t)SEG_B * SEG_L * sizeof(float);   // 12.8 MB
    unsigned* hist     = (unsigned*)p; p += (size_t)SEG_B * NB1 * sizeof(unsigned);  // 1 MB
    unsigned* cand_cnt = (unsigned*)p; p += (size_t)SEG_B * sizeof(unsigned);        // 256 B
    uint2*    bsel     = (uint2*)p;    p += (size_t)SEG_B * sizeof(uint2);           // 512 B
    uint2*    cand     = (uint2*)p;    p += (size_t)SEG_B * CAP * sizeof(uint2);     // 4 MB

    // Zero the atomically-accumulated regions (hist + cand_cnt are contiguous).
    hipMemsetAsync(hist, 0, (size_t)SEG_B * NB1 * sizeof(unsigned) + (size_t)SEG_B * sizeof(unsigned), stream);

    // Pass 1: attention scores + coarse histogram (reads 409.6 MB of x — the HBM floor).
    k_att<<<2048, 256, 0, stream>>>(x, w, bias, att, hist);

    // Pass 2: boundary digit via parallel suffix scan.
    k_bound<<<SEG_B, 1024, 0, stream>>>(hist, bsel);

    // Pass 3: candidate gather (digit >= b1), single warm pass over att.
    dim3 g3(SEG_B, 16);
    k_gather<<<g3, 256, 0, stream>>>(att, bsel, cand_cnt, cand);

    // Pass 4: exact select among candidates + gather/sum/normalize, all per-segment.
    k_phase2<<<SEG_B, 1024, 0, stream>>>(x, cand, cand_cnt, out);
}

// Round 3
// 778.079 us; speedup vs baseline: 1.3039x; 1.3039x over previous
//
#include <hip/hip_runtime.h>
#include <hip/hip_bf16.h>
#include <climits>

#define SEG_B 64
#define SEG_L 50000
#define SEG_D 32
#define TOPK  1024
#define NB1   4096      // round-1 bins (top 12 bits of ordkey)
#define CAP   8192      // per-segment candidate cap (expected ~2300)
#define CHUNKS 25       // k_att chunks per segment (2000 points each)
#define CHUNK_PTS (SEG_L / CHUNKS)

// Map float to uint32 such that larger float -> larger key (total order, no NaN in inputs).
__device__ __forceinline__ unsigned ordkey(float f) {
    unsigned u = __float_as_uint(f);
    return (u & 0x80000000u) ? ~u : (u | 0x80000000u);
}

// Pass 1: att[p] = dot(x[p,:32], w) + bias, plus per-SEGMENT 4096-bin histogram of
// the top-12 ordkey bits, built per-block in LDS and sparsely merged to global.
// Segment-aligned blocks: grid (B, CHUNKS); 8 lanes/point, float4 loads, 4x unroll.
__global__ void __launch_bounds__(256)
k_att(const float* __restrict__ x, const float* __restrict__ w,
      const float* __restrict__ bias, float* __restrict__ att,
      unsigned* __restrict__ ghist) {
    __shared__ unsigned lhist[NB1];
    #pragma unroll
    for (int i = threadIdx.x; i < NB1; i += 256) lhist[i] = 0u;
    __syncthreads();

    const int b     = blockIdx.x;
    const int lane  = threadIdx.x & 63;
    const int q     = lane & 7;          // which float4 of the 32-dim row
    const int sub   = lane >> 3;         // which of 8 points in this wave-group
    const int wave  = threadIdx.x >> 6;  // 4 waves per block
    const float4 wq = ((const float4*)w)[q];
    const float bb  = bias[0];
    const float4* x4 = (const float4*)x;

    const int segBase = b * SEG_L;
    const int start   = blockIdx.y * CHUNK_PTS;           // within segment
    const int end     = start + CHUNK_PTS;                // CHUNKS*CHUNK_PTS == SEG_L

    // offset covered: start + wave*8 + sub + 32*k  (complete, disjoint)
    for (int p0 = start + wave * 8 + sub; p0 < end; p0 += 128) {
        float d0 = 0.f, d1 = 0.f, d2 = 0.f, d3 = 0.f;
        const int p1 = p0 + 32, p2 = p0 + 64, p3 = p0 + 96;
        // 4 independent loads in flight
        float4 v0, v1, v2, v3;
        v0 = x4[((size_t)segBase + p0) * 8 + q];
        if (p1 < end) v1 = x4[((size_t)segBase + p1) * 8 + q];
        if (p2 < end) v2 = x4[((size_t)segBase + p2) * 8 + q];
        if (p3 < end) v3 = x4[((size_t)segBase + p3) * 8 + q];
        d0 = v0.x * wq.x + v0.y * wq.y + v0.z * wq.z + v0.w * wq.w;
        if (p1 < end) d1 = v1.x * wq.x + v1.y * wq.y + v1.z * wq.z + v1.w * wq.w;
        if (p2 < end) d2 = v2.x * wq.x + v2.y * wq.y + v2.z * wq.z + v2.w * wq.w;
        if (p3 < end) d3 = v3.x * wq.x + v3.y * wq.y + v3.z * wq.z + v3.w * wq.w;
        // 4 independent shfl-reduce chains (latency overlaps)
        d0 += __shfl_xor(d0, 1); d1 += __shfl_xor(d1, 1); d2 += __shfl_xor(d2, 1); d3 += __shfl_xor(d3, 1);
        d0 += __shfl_xor(d0, 2); d1 += __shfl_xor(d1, 2); d2 += __shfl_xor(d2, 2); d3 += __shfl_xor(d3, 2);
        d0 += __shfl_xor(d0, 4); d1 += __shfl_xor(d1, 4); d2 += __shfl_xor(d2, 4); d3 += __shfl_xor(d3, 4);
        if (q == 0) {
            float a0 = d0 + bb;
            att[segBase + p0] = a0;
            atomicAdd(&lhist[ordkey(a0) >> 20], 1u);
            if (p1 < end) { float a = d1 + bb; att[segBase + p1] = a; atomicAdd(&lhist[ordkey(a) >> 20], 1u); }
            if (p2 < end) { float a = d2 + bb; att[segBase + p2] = a; atomicAdd(&lhist[ordkey(a) >> 20], 1u); }
            if (p3 < end) { float a = d3 + bb; att[segBase + p3] = a; atomicAdd(&lhist[ordkey(a) >> 20], 1u); }
        }
    }
    __syncthreads();
    // Sparse merge: ~200 non-zero bins per block, contention depth = CHUNKS (25).
    for (int i = threadIdx.x; i < NB1; i += 256) {
        unsigned c = lhist[i];
        if (c) atomicAdd(&ghist[b * NB1 + i], c);
    }
}

// Pass 2: per-segment parallel suffix-scan of the 4096-bin histogram ->
// boundary digit b1 (smallest digit with suffix count >= TOPK).
__global__ void k_bound(const unsigned* __restrict__ hist, uint2* __restrict__ bsel) {
    const int b = blockIdx.x;
    const int t = threadIdx.x;       // 1024 threads, 4 bins each
    __shared__ unsigned sscan[1024];
    const uint4* h4 = (const uint4*)(hist + b * NB1);
    uint4 c = h4[t];                 // bins 4t..4t+3
    unsigned cl[4] = {c.x, c.y, c.z, c.w};
    unsigned gs = cl[0] + cl[1] + cl[2] + cl[3];
    sscan[t] = gs;
    __syncthreads();
    for (int off = 1; off < 1024; off <<= 1) {
        unsigned v = (t + off < 1024) ? sscan[t + off] : 0u;
        __syncthreads();
        sscan[t] += v;
        __syncthreads();
    }
    unsigned run = sscan[t] - gs;    // sum over bins strictly above this thread's bins
    #pragma unroll
    for (int j = 3; j >= 0; --j) {
        unsigned nr = run + cl[j];
        if (run < TOPK && nr >= TOPK) {
            bsel[b] = make_uint2((unsigned)(4 * t + j), (unsigned)(TOPK - run));
        }
        run = nr;
    }
}

// Pass 3: single warm pass over att; append (key, idx) for digit >= b1.
// Wave-aggregated cand_cnt atomics (one per wave-iteration, not per candidate).
__global__ void k_gather(const float* __restrict__ att, const uint2* __restrict__ bsel,
                         unsigned* __restrict__ cand_cnt, uint2* __restrict__ cand) {
    const int b = blockIdx.x;
    const unsigned b1 = bsel[b].x;
    const int lane = threadIdx.x & 63;
    const int per = (SEG_L + gridDim.y - 1) / gridDim.y;
    const int start = blockIdx.y * per;
    const int end = min(start + per, SEG_L);
    for (int i = start + (int)threadIdx.x; i < end; i += (int)blockDim.x) {
        unsigned key = ordkey(att[(size_t)b * SEG_L + i]);
        bool pred = (key >> 20) >= b1;
        unsigned long long mask = __ballot(pred);
        if (mask) {
            int leader = __ffsll((long long)mask) - 1;
            unsigned base = 0u;
            if (lane == leader) base = atomicAdd(&cand_cnt[b], (unsigned)__popcll(mask));
            base = (unsigned)__shfl((int)base, leader);
            if (pred) {
                unsigned off = (unsigned)__popcll(mask & ((1ull << lane) - 1ull));
                unsigned pos = base + off;
                if (pos < CAP) cand[b * CAP + pos] = make_uint2(key, (unsigned)i);
            }
        }
    }
}

// Pass 4: per-segment exact radix select over candidates (LDS, parallel scans),
// gather+sum selected rows, tie-break, mean over L, L2-normalize, write out.
__global__ void __launch_bounds__(1024)
k_phase2(const float* __restrict__ x, const uint2* __restrict__ cand,
         const unsigned* __restrict__ cand_cnt, float* __restrict__ out) {
    const int b = blockIdx.x;
    const int tid = threadIdx.x;     // 1024 threads
    __shared__ unsigned skey[CAP];
    __shared__ unsigned sidx[CAP];
    __shared__ unsigned hist[2048];
    __shared__ unsigned sscan[1024];
    __shared__ float    sred[32][33];
    __shared__ float    s_res[32];
    __shared__ int      s_eq[64];
    __shared__ int      s_eqsel[64];
    __shared__ unsigned s_prefix, s_k, s_eqn;
    __shared__ float    s_norm;

    const int cnt = min((int)cand_cnt[b], CAP);
    for (int c = tid; c < cnt; c += 1024) {
        uint2 v = cand[b * CAP + c];
        skey[c] = v.x; sidx[c] = v.y;
    }
    if (tid == 0) { s_prefix = 0u; s_k = TOPK; s_eqn = 0u; }
    __syncthreads();

    const unsigned shifts[3]   = {21u, 10u, 0u};
    const unsigned widths[3]   = {11u, 11u, 10u};
    const unsigned maskdone[3] = {0x00000000u, 0xFFE00000u, 0xFFFFFC00u};

    for (int r = 0; r < 3; ++r) {
        const unsigned shift = shifts[r];
        const int      nbins = 1 << widths[r];
        const unsigned dmask = (unsigned)nbins - 1u;
        const unsigned mdone = maskdone[r];
        const int      bpt   = nbins >> 10;             // bins per thread: 2 or 1
        for (int i = tid; i < nbins; i += 1024) hist[i] = 0u;
        __syncthreads();
        const unsigned prefix = s_prefix;
        const unsigned kneed  = s_k;
        for (int c = tid; c < cnt; c += 1024) {
            unsigned key = skey[c];
            if ((key & mdone) == prefix) atomicAdd(&hist[(key >> shift) & dmask], 1u);
        }
        __syncthreads();
        unsigned cl[2] = {0u, 0u};
        unsigned gs = 0u;
        for (int j = 0; j < bpt; ++j) { cl[j] = hist[tid * bpt + j]; gs += cl[j]; }
        sscan[tid] = gs;
        __syncthreads();
        for (int off = 1; off < 1024; off <<= 1) {
            unsigned v = (tid + off < 1024) ? sscan[tid + off] : 0u;
            __syncthreads();
            sscan[tid] += v;
            __syncthreads();
        }
        unsigned run = sscan[tid] - gs;                  // strictly above this thread's bins
        for (int j = bpt - 1; j >= 0; --j) {
            unsigned nr = run + cl[j];
            if (run < kneed && nr >= kneed) {
                s_prefix = prefix | ((unsigned)(tid * bpt + j) << shift);
                s_k = kneed - run;
            }
            run = nr;
        }
        __syncthreads();
    }

    const unsigned tk = s_prefix;                        // threshold key
    const int m = (int)s_k;                              // equals needed

    // Sum rows with key > tk: 32 row-groups x 32 dims (each 32-lane group reads one
    // 128B row coalesced).
    const int rg = tid >> 5, d = tid & 31;
    float part = 0.0f;
    for (int c = rg; c < cnt; c += 32) {
        if (skey[c] > tk) part += x[((size_t)b * SEG_L + sidx[c]) * SEG_D + d];
    }
    sred[rg][d] = part;
    // Collect indices equal to threshold.
    for (int c = tid; c < cnt; c += 1024) {
        if (skey[c] == tk) {
            unsigned p = atomicAdd(&s_eqn, 1u);
            if (p < 64u) s_eq[p] = (int)sidx[c];
        }
    }
    __syncthreads();
    if (tid == 0) {
        int eqn = (int)min(s_eqn, 64u);
        int mm = min(m, eqn);
        int last = -1;
        for (int j = 0; j < mm; ++j) {                   // m is ~1; tiny serial select
            int best = INT_MAX;
            for (int t2 = 0; t2 < eqn; ++t2) {
                int v = s_eq[t2];
                if (v > last && v < best) best = v;
            }
            s_eqsel[j] = best;
            last = best;
        }
    }
    __syncthreads();
    if (tid < 32) {
        float s = 0.0f;
        for (int r2 = 0; r2 < 32; ++r2) s += sred[r2][tid];
        int eqn = (int)min(s_eqn, 64u);
        int mm = min(m, eqn);
        for (int j = 0; j < mm; ++j) {
            int row = s_eqsel[j];
            if (row != INT_MAX) s += x[((size_t)b * SEG_L + row) * SEG_D + tid];
        }
        s_res[tid] = s / (float)SEG_L;
    }
    __syncthreads();
    if (tid == 0) {
        float n = 0.0f;
        for (int i = 0; i < SEG_D; ++i) n += s_res[i] * s_res[i];
        s_norm = sqrtf(n);
    }
    __syncthreads();
    if (tid < 32) out[b * SEG_D + tid] = s_res[tid] / fmaxf(s_norm, 1e-12f);
}

extern "C" void kernel_launch(void* const* d_in, const int* in_sizes, int n_in,
                              void* d_out, int out_size, void* d_ws, size_t ws_size,
                              hipStream_t stream) {
    const float* x    = (const float*)d_in[0];   // [B*L, 32] fp32
    // d_in[1] = length (int32[64]) — constant L, unused
    const float* w    = (const float*)d_in[2];   // [32]
    const float* bias = (const float*)d_in[3];   // [1]
    float* out = (float*)d_out;                  // [64, 32]

    // Workspace layout (regions well-aligned by construction):
    char* p = (char*)d_ws;
    float*    att      = (float*)p;    p += (size_t)SEG_B * SEG_L * sizeof(float);   // 12.8 MB
    unsigned* ghist    = (unsigned*)p; p += (size_t)SEG_B * NB1 * sizeof(unsigned);  // 1 MB
    unsigned* cand_cnt = (unsigned*)p; p += (size_t)SEG_B * sizeof(unsigned);        // 256 B
    uint2*    bsel     = (uint2*)p;    p += (size_t)SEG_B * sizeof(uint2);           // 512 B
    uint2*    cand     = (uint2*)p;    p += (size_t)SEG_B * CAP * sizeof(uint2);     // 4 MB

    // Zero the atomically-accumulated regions (ghist + cand_cnt are contiguous).
    hipMemsetAsync(ghist, 0, (size_t)SEG_B * NB1 * sizeof(unsigned) + (size_t)SEG_B * sizeof(unsigned), stream);

    // Pass 1: attention scores + LDS-built coarse histogram (reads 409.6 MB of x).
    dim3 g1(SEG_B, CHUNKS);
    k_att<<<g1, 256, 0, stream>>>(x, w, bias, att, ghist);

    // Pass 2: boundary digit via parallel suffix scan.
    k_bound<<<SEG_B, 1024, 0, stream>>>(ghist, bsel);

    // Pass 3: candidate gather (digit >= b1), wave-aggregated append.
    dim3 g3(SEG_B, 16);
    k_gather<<<g3, 256, 0, stream>>>(att, bsel, cand_cnt, cand);

    // Pass 4: exact select among candidates + gather/sum/normalize, per-segment.
    k_phase2<<<SEG_B, 1024, 0, stream>>>(x, cand, cand_cnt, out);
}